// Round 1
// 586.398 us; speedup vs baseline: 1.1106x; 1.1106x over previous
//
#include <hip/hip_runtime.h>
#include <math.h>

#define HH 1024
#define AA 180
#define BB 16
#define NCOL (BB*AA)          // 2880 (b,angle) columns
#define RSP 1028              // pair-row stride (float2 entries)
#define GUARD 48              // fallback path: zero guard floats each side
#define RS 1120               // fallback row stride
#define PI_D 3.14159265358979323846

#define GANG 45               // angles staged per group (180 = 4*45)
#define WIN 48                // window entries (float2) per angle

// ws float-offsets
#define OFF_CG   0            // 512 filter coeffs
#define OFF_CST  512          // float4[180]: (512c, 512s, D8=-8*DEL*512*s, 0)
#define OFF_CST2 1232         // float2[180]: (c,s) fallback table
#define OFF_DATA 1600         // pair rows (float2[NCOL*RSP]) or fallback xaf

__device__ __forceinline__ float fractf_(float x) {
#if __has_builtin(__builtin_amdgcn_fractf)
    return __builtin_amdgcn_fractf(x);   // v_fract_f32
#else
    return x - floorf(x);
#endif
}

// ---------------- tables ----------------
__global__ __launch_bounds__(512) void k_tables(float* __restrict__ ws) {
    int t = threadIdx.x;
    if (t < 512) {
        double d = 2.0 * t + 1.0;
        ws[OFF_CG + t] = (float)(-2.0 / (PI_D * PI_D * d * d));
    }
    if (t < AA) {
        float thf = (float)t * 0.017453292519943295f;  // fp32(pi/180)
        double th = (double)thf;
        double c = cos(th), s = sin(th);
        float4* cst4 = (float4*)(ws + OFF_CST);
        // D8 = d(iy)/d(k) for y-step of 8 pixels: -8*DEL*512*s = -(8192/1023)*s
        cst4[t] = make_float4((float)(512.0 * c), (float)(512.0 * s),
                              (float)(-(8192.0 / 1023.0) * s), 0.f);
        float2* cst2 = (float2*)(ws + OFF_CST2);
        cst2[t] = make_float2((float)(512.0 * c), (float)(512.0 * s));
    }
}

// ---------------- shared conv core (fused angle-interp + ramp filter) ----------------
__device__ __forceinline__ void filter_core(const float* __restrict__ x,
                                            const float* __restrict__ cg,
                                            float* xsp, int t, int col,
                                            float acc[16]) {
    int b = col / AA, a = col - b * AA;

    float4* z4 = (float4*)xsp;
    #pragma unroll
    for (int i = t; i < 816; i += 64) z4[i] = make_float4(0.f, 0.f, 0.f, 0.f);
    __syncthreads();

    float ixf = (float)a * (float)(180.0/179.0) - 0.5f;
    float fl = floorf(ixf);
    int i0 = (int)fl;
    float fx = ixf - fl;
    float w0 = (i0 >= 0)      ? (1.0f - fx) : 0.0f;
    float w1 = (i0 + 1 < AA)  ? fx          : 0.0f;
    int c0 = max(i0, 0);
    int c1 = min(i0 + 1, AA - 1);
    const float* xb = x + (size_t)b * HH * AA;
    for (int i = t; i < HH; i += 64) {
        float v = w0 * xb[i * AA + c0] + w1 * xb[i * AA + c1];
        int q = 1024 + i;
        xsp[q + (q >> 4)] = v;         // lane stride 17 -> conflict-free
    }
    __syncthreads();

    int pp = 17 * t;
    float Lw[16], Rw[16];
    #pragma unroll
    for (int m = 0; m < 16; ++m) {
        int f = 1024 + m;
        acc[m] = 0.5f * xsp[pp + f + (f >> 4)];
    }
    #pragma unroll
    for (int m = 0; m < 16; ++m) {
        int f = 1 + m;
        Lw[(m + 1) & 15] = xsp[pp + f + (f >> 4)];
        int g = 2047 + m;
        Rw[(m - 1) & 15] = xsp[pp + g + (g >> 4)];
    }

    for (int it0 = 0; it0 < 512; it0 += 8) {
        #pragma unroll
        for (int u = 0; u < 8; ++u) {
            int it = it0 + u;
            float cv = cg[511 - it];
            #pragma unroll
            for (int m = 0; m < 16; ++m) {
                acc[m] = fmaf(cv, Lw[(m + 2*u + 1) & 15] + Rw[(m - 2*u - 1) & 15], acc[m]);
            }
            int fL  = 2*it + 17;
            Lw[(2*u + 1) & 15] = xsp[pp + fL  + (fL  >> 4)];
            int fL2 = 2*it + 18;
            Lw[(2*u + 2) & 15] = xsp[pp + fL2 + (fL2 >> 4)];
            int fR  = 2045 - 2*it;
            Rw[(13 - 2*u) & 15] = xsp[pp + fR  + (fR  >> 4)];
            int fR2 = 2046 - 2*it;
            Rw[(14 - 2*u) & 15] = xsp[pp + fR2 + (fR2 >> 4)];
        }
    }
}

// ---------------- pair-output filter (SLOPE layout) ----------------
// pair[s] = (y[s-2], y[s-1]-y[s-2]) * SC, zero outside; valid s in [0,1026].
// Lerp consumer: v + f*dv  ==  fmaf(f, d.y, acc + d.x)  (bit-identical to the
// previous runtime d.y-d.x form: same operands, same rounding).
__global__ __launch_bounds__(64) void k_filter_pair(const float* __restrict__ x,
                                                    const float* __restrict__ cg,
                                                    float2* __restrict__ pair) {
    __shared__ float xsp[3264];
    int t = threadIdx.x;
    int col = blockIdx.x;
    float acc[16];
    filter_core(x, cg, xsp, t, col, acc);

    const float SC = (float)(PI_D / 360.0);
    float yv[16];
    #pragma unroll
    for (int m = 0; m < 16; ++m) yv[m] = acc[m] * SC;
    float ynext = __shfl_down(yv[0], 1);
    if (t == 63) ynext = 0.f;

    float2* rowp = pair + (size_t)col * RSP;
    int s0 = 16 * t + 2;
    #pragma unroll
    for (int m = 0; m < 15; ++m) rowp[s0 + m] = make_float2(yv[m], yv[m + 1] - yv[m]);
    rowp[s0 + 15] = make_float2(yv[15], ynext - yv[15]);
    if (t == 0) {
        rowp[0] = make_float2(0.f, 0.f);
        rowp[1] = make_float2(0.f, yv[0]);     // (v=0, dv=y0-0)
    }
    if (t == 63) rowp[1026] = make_float2(0.f, 0.f);
}

// ---------------- LDS-staged backprojection ----------------
// 32x32 px tile per block, 256 threads, 4 y-px/thread (y = y0+ty+8k).
// Angles in 4 groups of 45. Per group: per-angle constants (c,s,D8,bf) staged
// into LDS float4 (NO s_load in the hot loop -> DS-only, in-order, so the
// compiler can use fine-grained lgkmcnt(N) instead of full lgkmcnt(0) drains),
// plus 48-entry float2 slope windows staged via float4 loads (base even-aligned).
__global__ __launch_bounds__(256, 4) void k_bproj_lds(const float* __restrict__ ws,
                                                      const float2* __restrict__ pair,
                                                      float* __restrict__ out) {
    __shared__ float4 winbuf[GANG * (WIN/2)];   // 17280 B, 16B-aligned
    __shared__ float4 angf4[GANG];              // (512c, 512s, D8, bf)
    __shared__ int    baseL[GANG];

    const float4* cst = (const float4*)(ws + OFF_CST);
    int t = threadIdx.x;
    int n = blockIdx.x;
    // XCD-batch swizzle: blocks ≡ i (mod 8) handle batches {i, i+8} -> per-XCD
    // pair working set ~3 MB -> L2-resident.
    int b    = (n & 7) + 8 * ((n >> 3) & 1);
    int tile = n >> 4;                  // [0,1024)
    int bx = tile & 31;                 // x-tile (32 px)
    int by = tile >> 5;                 // y-tile (32 px)
    int tx = t & 31;
    int ty = t >> 5;                    // [0,8)
    int xg = bx * 32 + tx;
    int y0 = by * 32;
    int yg = y0 + ty;                   // pixel k at yg + 8k

    const float DEL = (float)(2.0 / 1023.0);
    // bit-exact jnp.linspace replication (mul then add, no contraction)
    float ux  = __fadd_rn(__fmul_rn((float)xg, DEL), -1.0f);
    float uy  = __fadd_rn(__fmul_rn((float)yg, DEL), -1.0f);
    float nuy = -uy;

    // tile-uniform corner coords
    float cxl = __fadd_rn(__fmul_rn((float)(bx*32),      DEL), -1.0f);
    float cxh = __fadd_rn(__fmul_rn((float)(bx*32 + 31), DEL), -1.0f);
    float cyl = __fadd_rn(__fmul_rn((float)(y0),         DEL), -1.0f);
    float cyh = __fadd_rn(__fmul_rn((float)(y0 + 31),    DEL), -1.0f);

    float minax = (cxl <= 0.f && cxh >= 0.f) ? 0.f : fminf(fabsf(cxl), fabsf(cxh));
    float minay = (cyl <= 0.f && cyh >= 0.f) ? 0.f : fminf(fabsf(cyl), fabsf(cyh));
    float rmin2 = minax * minax + minay * minay;
    float maxax = fmaxf(fabsf(cxl), fabsf(cxh));
    float maxay = fmaxf(fabsf(cyl), fabsf(cyh));
    float rmax2 = maxax * maxax + maxay * maxay;

    size_t o0 = ((size_t)b << 20) + ((size_t)yg << 10) + (size_t)xg;
    float* p0 = out + o0;

    if (rmin2 > 1.000001f) {            // tile fully outside: zeros, no barriers hit
        p0[0] = 0.f; p0[8 << 10] = 0.f; p0[16 << 10] = 0.f; p0[24 << 10] = 0.f;
        return;
    }

    bool interior = (rmax2 <= 0.9999f);
    const float2* slab = pair + (size_t)b * (AA * RSP);
    const float2* win = (const float2*)winbuf;
    float a0 = 0.f, a1 = 0.f, a2 = 0.f, a3 = 0.f;
    float nyl = -cyl, nyh = -cyh;

    for (int g0 = 0; g0 < AA; g0 += GANG) {
        // --- per-angle window bases + constants (tile-uniform) ---
        if (t < GANG) {
            float4 cs = cst[g0 + t];    // vector load (t varies)
            float mpx = fminf(cxl * cs.x, cxh * cs.x);
            float mpy = fminf(nyl * cs.y, nyh * cs.y);
            float minP = mpx + mpy + 513.5f;
            int base = (int)floorf(minP) - 1;
            base = min(max(base, 0), 1027 - WIN);
            base &= ~1;                 // 16B-align window for float4 staging
            baseL[t] = base;
            angf4[t] = make_float4(cs.x, cs.y, cs.z, 513.5f - (float)base);
        }
        __syncthreads();

        // --- coalesced staging: 45 angles x 24 float4 (48 float2) ---
        for (int idx = t; idx < GANG * (WIN/2); idx += 256) {
            int al = idx / (WIN/2);
            int w  = idx - (WIN/2) * al;
            const float4* rp4 = (const float4*)(slab + (size_t)(g0 + al) * RSP + baseL[al]);
            winbuf[idx] = rp4[w];
        }
        __syncthreads();

        // --- compute 45 angles from LDS (DS-only loop) ---
        if (interior) {
            #pragma unroll 5
            for (int g = 0; g < GANG; ++g) {
                float4 cb = angf4[g];           // one ds_read_b128 broadcast
                float P0 = fmaf(ux, cb.x, fmaf(nuy, cb.y, cb.w));
                float P1 = P0 + cb.z;
                float P2 = fmaf(2.0f, cb.z, P0);
                float P3 = P2 + cb.z;
                int j0 = (int)P0, j1 = (int)P1, j2 = (int)P2, j3 = (int)P3;
                const float2* wg = win + g * WIN;
                float2 d0 = wg[j0];
                float2 d1 = wg[j1];
                float2 d2 = wg[j2];
                float2 d3 = wg[j3];
                float f0 = fractf_(P0), f1 = fractf_(P1), f2v = fractf_(P2), f3 = fractf_(P3);
                a0 = fmaf(f0, d0.y, a0 + d0.x);
                a1 = fmaf(f1, d1.y, a1 + d1.x);
                a2 = fmaf(f2v, d2.y, a2 + d2.x);
                a3 = fmaf(f3, d3.y, a3 + d3.x);
            }
        } else {
            #pragma unroll 5
            for (int g = 0; g < GANG; ++g) {
                float4 cb = angf4[g];
                float P0 = fmaf(ux, cb.x, fmaf(nuy, cb.y, cb.w));
                float P1 = P0 + cb.z;
                float P2 = fmaf(2.0f, cb.z, P0);
                float P3 = P2 + cb.z;
                int j0 = (int)P0, j1 = (int)P1, j2 = (int)P2, j3 = (int)P3;
                j0 = min(max(j0, 0), WIN - 1); j1 = min(max(j1, 0), WIN - 1);
                j2 = min(max(j2, 0), WIN - 1); j3 = min(max(j3, 0), WIN - 1);
                const float2* wg = win + g * WIN;
                float2 d0 = wg[j0];
                float2 d1 = wg[j1];
                float2 d2 = wg[j2];
                float2 d3 = wg[j3];
                float f0 = fractf_(P0), f1 = fractf_(P1), f2v = fractf_(P2), f3 = fractf_(P3);
                a0 = fmaf(f0, d0.y, a0 + d0.x);
                a1 = fmaf(f1, d1.y, a1 + d1.x);
                a2 = fmaf(f2v, d2.y, a2 + d2.x);
                a3 = fmaf(f3, d3.y, a3 + d3.x);
            }
        }
        __syncthreads();   // protect baseL/angf4/win before next group
    }

    if (interior) {
        p0[0] = a0; p0[8 << 10] = a1; p0[16 << 10] = a2; p0[24 << 10] = a3;
    } else {
        // bit-exact circle mask per pixel (in-circle px had exact j/fract; out px masked)
        float uy1 = __fadd_rn(__fmul_rn((float)(yg + 8),  DEL), -1.0f);
        float uy2 = __fadd_rn(__fmul_rn((float)(yg + 16), DEL), -1.0f);
        float uy3 = __fadd_rn(__fmul_rn((float)(yg + 24), DEL), -1.0f);
        float xx = __fmul_rn(ux, ux);
        float r20 = __fadd_rn(xx, __fmul_rn(uy,  uy));
        float r21 = __fadd_rn(xx, __fmul_rn(uy1, uy1));
        float r22 = __fadd_rn(xx, __fmul_rn(uy2, uy2));
        float r23 = __fadd_rn(xx, __fmul_rn(uy3, uy3));
        p0[0]        = (r20 <= 1.0f) ? a0 : 0.f;
        p0[8 << 10]  = (r21 <= 1.0f) ? a1 : 0.f;
        p0[16 << 10] = (r22 <= 1.0f) ? a2 : 0.f;
        p0[24 << 10] = (r23 <= 1.0f) ? a3 : 0.f;
    }
}

// ================= fallback path (R3, proven) — used if ws too small ==========
__global__ __launch_bounds__(64) void k_filter_sc(const float* __restrict__ x,
                                                  const float* __restrict__ cg,
                                                  float* __restrict__ xaf) {
    __shared__ float xsp[3264];
    int t = threadIdx.x;
    int col = blockIdx.x;
    float acc[16];
    filter_core(x, cg, xsp, t, col, acc);

    const float SC = (float)(PI_D / 360.0);
    float* rb = xaf + (size_t)col * RS;
    if (t < 12)            ((float4*)rb)[t]              = make_float4(0.f,0.f,0.f,0.f);
    else if (t < 24)       ((float4*)rb)[268 + (t - 12)] = make_float4(0.f,0.f,0.f,0.f);
    float4* o4 = (float4*)(rb + GUARD + 16 * t);
    #pragma unroll
    for (int m4 = 0; m4 < 4; ++m4)
        o4[m4] = make_float4(acc[4*m4]*SC, acc[4*m4+1]*SC, acc[4*m4+2]*SC, acc[4*m4+3]*SC);
}

__global__ __launch_bounds__(256, 4) void k_bproj_sc(const float* __restrict__ ws,
                                                     const float* __restrict__ xaf,
                                                     float* __restrict__ out) {
    const float2* cst2 = (const float2*)(ws + OFF_CST2);
    int t = threadIdx.x;
    int tx = t & 15, ty = t >> 4;
    int bx = blockIdx.x, by = blockIdx.y, b = blockIdx.z;
    int xg = bx * 16 + tx, yg = by * 16 + ty;
    const float DEL = (float)(2.0 / 1023.0);
    float ux = __fadd_rn(__fmul_rn((float)xg, DEL), -1.0f);
    float uy = __fadd_rn(__fmul_rn((float)yg, DEL), -1.0f);

    float cx0 = __fadd_rn(__fmul_rn((float)(bx*16),      DEL), -1.0f);
    float cx1 = __fadd_rn(__fmul_rn((float)(bx*16 + 15), DEL), -1.0f);
    float cy0 = __fadd_rn(__fmul_rn((float)(by*16),      DEL), -1.0f);
    float cy1 = __fadd_rn(__fmul_rn((float)(by*16 + 15), DEL), -1.0f);
    float minax = (cx0 <= 0.f && cx1 >= 0.f) ? 0.f : fminf(fabsf(cx0), fabsf(cx1));
    float minay = (cy0 <= 0.f && cy1 >= 0.f) ? 0.f : fminf(fabsf(cy0), fabsf(cy1));
    float rmin2 = minax * minax + minay * minay;

    size_t oidx = ((size_t)b << 20) + ((size_t)yg << 10) + (size_t)xg;
    if (rmin2 > 1.000001f) { out[oidx] = 0.f; return; }

    const float* row = xaf + (size_t)b * (AA * RS);
    const float BIAS = 511.5f + (float)GUARD;
    float nuy = -uy;
    float acc = 0.f;

    #pragma unroll 4
    for (int a = 0; a < AA; ++a) {
        float2 cs = cst2[a];
        float iy = fmaf(ux, cs.x, fmaf(nuy, cs.y, BIAS));
        int j = (int)iy;
        float fy = fractf_(iy);
        float v0 = row[j];
        float v1 = row[j + 1];
        acc = fmaf(fy, v1 - v0, acc + v0);
        row += RS;
    }

    float r2 = __fadd_rn(__fmul_rn(ux, ux), __fmul_rn(uy, uy));
    out[oidx] = (r2 <= 1.0f) ? acc : 0.f;
}

extern "C" void kernel_launch(void* const* d_in, const int* in_sizes, int n_in,
                              void* d_out, int out_size, void* d_ws, size_t ws_size,
                              hipStream_t stream) {
    const float* x = (const float*)d_in[0];
    float* out = (float*)d_out;
    float* ws = (float*)d_ws;
    float* cg  = ws + OFF_CG;

    hipLaunchKernelGGL(k_tables, dim3(1), dim3(512), 0, stream, ws);

    size_t need_pair = (size_t)OFF_DATA * 4 + (size_t)NCOL * RSP * sizeof(float2);
    if (ws_size >= need_pair) {
        float2* pair = (float2*)(ws + OFF_DATA);
        hipLaunchKernelGGL(k_filter_pair, dim3(NCOL), dim3(64), 0, stream, x, cg, pair);
        hipLaunchKernelGGL(k_bproj_lds, dim3(16384), dim3(256), 0, stream, ws, pair, out);
    } else {
        float* xaf = ws + OFF_DATA;
        hipLaunchKernelGGL(k_filter_sc, dim3(NCOL), dim3(64), 0, stream, x, cg, xaf);
        hipLaunchKernelGGL(k_bproj_sc, dim3(64, 64, BB), dim3(256), 0, stream, ws, xaf, out);
    }
}